// Round 14
// baseline (107.482 us; speedup 1.0000x reference)
//
#include <hip/hip_runtime.h>

// ---- types -----------------------------------------------------------------
typedef __bf16 bf16;
typedef __attribute__((ext_vector_type(8))) __bf16 bf16x8;
typedef __attribute__((ext_vector_type(4))) __bf16 bf16x4;
typedef __attribute__((ext_vector_type(4))) float  f32x4;

static __device__ __forceinline__ f32x4 mfma16(bf16x8 a, bf16x8 b, f32x4 c) {
  return __builtin_amdgcn_mfma_f32_16x16x32_bf16(a, b, c, 0, 0, 0);
}
static __device__ __forceinline__ float fexp2(float x) {
  return __builtin_amdgcn_exp2f(x);
}
static __device__ __forceinline__ float flog2(float x) {
  return __builtin_amdgcn_logf(x);
}

// exp(s/sqrt(128)) = exp2(s * C1). C1 folded into Wq/bq at prep time.
#define EXP_C1 (1.4426950408889634f / 11.313708498984760f)

// async global->LDS, 16B/lane; dst base is wave-uniform, HW adds lane*16.
typedef const __attribute__((address_space(1))) unsigned int gas_u32;
typedef __attribute__((address_space(3))) unsigned int las_u32;
#define GLDS16(gp, lp) __builtin_amdgcn_global_load_lds((gas_u32*)(gp), (las_u32*)(lp), 16, 0, 0)

// RACE FIX (keep): drain own vmcnt BEFORE s_barrier so cross-wave DMA
// completion is guaranteed.
#define WAITN0() __asm__ volatile("s_waitcnt vmcnt(0)" ::: "memory")

// Granule-major tile (128 rows x 128 cols bf16, 32KB): elem(r,c) = (c>>3)*1024 + r*8 + (c&7).
// V is ROW-PERMUTED (k_qkv epilogue) so the PV MFMA consumes the QK^T
// C-fragment from registers: slot (quad,e) of 32-block s holds V row
// k = 32s + quad*4 + (e&3) + 16*(e>>2).
//
// XCD SWIZZLE: k_stats/k_attn grids are (64 b, 8 qt) with b on X. Same-b
// blocks have linear ids stride 64 (== 0 mod 8 XCDs) -> same XCD L2.
//
// r19->r20: k_qkv rebuilt as NO-LDS, FUSED, BARRIER-FREE. Session evidence
// eliminated occupancy (r7/r8), staging (r18: clean zero-reg staging, dur
// unchanged) and W-latency alone (r19 ~neutral) -> the binder is the
// stage->barrier->compute convoy + 3 serial passes over one LDS tile.
// Now: each wave reads q fragments directly from global fp32 (128B-contig
// row chunks; 4-wave redundancy -> L2, 262MB total ~ 10TB/s << ceiling),
// converts inline, feeds Q/K/V accs from ONE ax load (kk-fused, r12-
// verified math, r16-verified epilogues). Zero barriers, zero LDS.
// bounds(256,3) -> 170-VGPR cap for ~150 est. Spill signature to watch:
// VGPR >= 168 or WRITE >> 49MB -> revert.

// ============================================================================
// Kernel 0: prep. W[3][128][256] fp32 -> Wc[3][32 g][128 n][8] bf16.
// Wq additionally scaled by C1. Also initializes out[8192] = -inf for the
// k_attn atomic-max epilogue.
// ============================================================================
__global__ __launch_bounds__(256) void k_prep(
    const float* __restrict__ Wq, const float* __restrict__ Wk,
    const float* __restrict__ Wv, bf16* __restrict__ Wc, float* __restrict__ out)
{
  int id = blockIdx.x * 256 + threadIdx.x;      // 48 blocks = 3*4096
  if (id < 8192) out[id] = -__builtin_inff();
  int proj = id >> 12, r = id & 4095;
  int g = r >> 7, n = r & 127;
  const float* W = proj == 0 ? Wq : proj == 1 ? Wk : Wv;
  const float sc = (proj == 0) ? EXP_C1 : 1.0f;
  const float4* src = (const float4*)(W + n * 256 + g * 8);
  float4 a = src[0], b = src[1];
  bf16x8 o = { (bf16)(a.x * sc), (bf16)(a.y * sc), (bf16)(a.z * sc), (bf16)(a.w * sc),
               (bf16)(b.x * sc), (bf16)(b.y * sc), (bf16)(b.z * sc), (bf16)(b.w * sc) };
  *(bf16x8*)(Wc + (size_t)proj * 32768 + g * 1024 + n * 8) = o;
}

// ============================================================================
// Kernel 1: QKV projection, fused + no-LDS + barrier-free.
// grid(1024) x 256 thr (4 waves, 1x4 col split), 3 blocks/CU (170-VGPR cap).
// Per kk: ax[4] read from q GLOBAL (fp32->bf16 inline), 6 W-frags, 24 MFMA.
// ============================================================================
__global__ __launch_bounds__(256, 3) void k_qkv(
    const float* __restrict__ q, const bf16* __restrict__ Wc,
    const float* __restrict__ bq, const float* __restrict__ bk, const float* __restrict__ bv,
    bf16* __restrict__ Qb, bf16* __restrict__ Kb, bf16* __restrict__ VT)
{
  const int tid = threadIdx.x, lane = tid & 63, wave = tid >> 6;
  const int ln = lane & 15, quad = lane >> 4;
  const int wc = wave;                          // 1x4 waves: 64 rows x 32 cols
  const int m0 = blockIdx.x * 64;
  const float* qt = q + (size_t)m0 * 256;

  const int b = m0 >> 10, st = (m0 & 1023) >> 7, s_off = m0 & 64;
  const size_t tbase = ((size_t)b * 8 + st) * 16384;

  f32x4 aQ[2][4] = {}, aK[2][4] = {}, aV[4][2] = {};
  #pragma unroll
  for (int kk = 0; kk < 8; ++kk) {
    bf16x8 ax[4];
    #pragma unroll
    for (int t = 0; t < 4; ++t) {
      // row t*16+ln, cols kk*32+quad*8 .. +8 (fp32): 2x float4, 128B/row-group
      const float* rp = qt + (size_t)(t * 16 + ln) * 256 + kk * 32 + quad * 8;
      float4 a0 = *(const float4*)rp;
      float4 a1 = *(const float4*)(rp + 4);
      ax[t] = bf16x8{ (bf16)a0.x, (bf16)a0.y, (bf16)a0.z, (bf16)a0.w,
                      (bf16)a1.x, (bf16)a1.y, (bf16)a1.z, (bf16)a1.w };
    }
    bf16x8 bwQ[2], bwK[2], bwV[2];
    #pragma unroll
    for (int t2 = 0; t2 < 2; ++t2) {
      const int off = (kk * 4 + quad) * 1024 + (wc * 32 + t2 * 16 + ln) * 8;
      bwQ[t2] = *(const bf16x8*)(Wc + off);
      bwK[t2] = *(const bf16x8*)(Wc + 32768 + off);
      bwV[t2] = *(const bf16x8*)(Wc + 65536 + off);
    }
    __builtin_amdgcn_s_setprio(1);
    #pragma unroll
    for (int i = 0; i < 2; ++i)
      #pragma unroll
      for (int j = 0; j < 4; ++j) {
        aQ[i][j] = mfma16(bwQ[i], ax[j], aQ[i][j]);   // D[d][s]
        aK[i][j] = mfma16(bwK[i], ax[j], aK[i][j]);
      }
    #pragma unroll
    for (int i = 0; i < 4; ++i)
      #pragma unroll
      for (int j = 0; j < 2; ++j)
        aV[i][j] = mfma16(ax[i], bwV[j], aV[i][j]);   // D[s][d]
    __builtin_amdgcn_s_setprio(0);
  }

  // Q,K epilogue: granule-major [s][d]; regs = 4 consecutive d -> bf16x4
  for (int p = 0; p < 2; ++p) {
    bf16* dst = (p == 0 ? Qb : Kb) + tbase;
    const float* bias = p == 0 ? bq : bk;
    for (int i = 0; i < 2; ++i) {
      float4 b4 = *(const float4*)&bias[wc * 32 + i * 16 + quad * 4];
      if (p == 0) { b4.x *= EXP_C1; b4.y *= EXP_C1; b4.z *= EXP_C1; b4.w *= EXP_C1; }
      int gd = wc * 4 + i * 2 + (quad >> 1);    // d-granule
      int e0 = (quad & 1) * 4;
      for (int j = 0; j < 4; ++j) {
        int s = s_off + j * 16 + ln;
        const f32x4 a_ = p == 0 ? aQ[i][j] : aK[i][j];
        bf16x4 o = { (bf16)(a_[0] + b4.x), (bf16)(a_[1] + b4.y),
                     (bf16)(a_[2] + b4.z), (bf16)(a_[3] + b4.w) };
        *(bf16x4*)&dst[(size_t)gd * 1024 + (size_t)s * 8 + e0] = o;
      }
    }
  }
  { // V epilogue: [s-granule][d][8], ROW-PERMUTED
    bf16* dst = VT + tbase;
    for (int j = 0; j < 2; ++j) {
      int d = wc * 32 + j * 16 + ln;
      float bb = bv[d];
      for (int i = 0; i < 4; ++i) {
        int s0 = s_off + i * 16 + quad * 4;
        int G  = (s0 >> 5) * 4 + ((s0 & 15) >> 2);
        int e0 = (s0 & 16) >> 2;
        bf16x4 o = { (bf16)(aV[i][j][0] + bb), (bf16)(aV[i][j][1] + bb),
                     (bf16)(aV[i][j][2] + bb), (bf16)(aV[i][j][3] + bb) };
        *(bf16x4*)&dst[(size_t)G * 1024 + (size_t)d * 8 + e0] = o;
      }
    }
  }
}

// ============================================================================
// Kernel 2: column stats. grid(64 b, 8 kt), block 256, 2 blocks/CU.
// K-frags register-resident; Q streamed via double-buffered DMA.
// Writes nlg[k] = -log2(colsum) (consumed as QK accumulator init in k_attn).
// ============================================================================
__global__ __launch_bounds__(256, 2) void k_stats(
    const bf16* __restrict__ Qb, const bf16* __restrict__ Kb, float* __restrict__ nlg)
{
  __shared__ char Qbuf[2][32768];
  const int b = blockIdx.x, kt = blockIdx.y;
  const int tid = threadIdx.x, lane = tid & 63, wave = tid >> 6;
  const int ln = lane & 15, quad = lane >> 4;

  const bf16* ktile = Kb + ((size_t)b * 8 + kt) * 16384;
  bf16x8 ak[2][4];                              // wave's 32 k-rows, full d=128
  for (int i = 0; i < 2; ++i)
    for (int kk = 0; kk < 4; ++kk)
      ak[i][kk] = *(const bf16x8*)(ktile + (kk * 4 + quad) * 1024 + (wave * 32 + i * 16 + ln) * 8);

  const char* qb_b = (const char*)(Qb + (size_t)b * 8 * 16384);
  for (int c = 0; c < 8; ++c)                   // prologue DMA q-tile 0
    GLDS16(qb_b + (wave * 8 + c) * 1024 + lane * 16, &Qbuf[0][(wave * 8 + c) * 1024]);

  f32x4 csum[2] = {};
  for (int qt = 0; qt < 8; ++qt) {
    WAITN0();
    __syncthreads();                            // all waves' DMA(qt) complete
    if (qt < 7)
      for (int c = 0; c < 8; ++c)
        GLDS16(qb_b + (size_t)(qt + 1) * 32768 + (wave * 8 + c) * 1024 + lane * 16,
               &Qbuf[(qt + 1) & 1][(wave * 8 + c) * 1024]);
    const char* Ql = Qbuf[qt & 1];
    for (int jq = 0; jq < 8; ++jq) {
      f32x4 s0 = {}, s1 = {};
      __builtin_amdgcn_s_setprio(1);
      for (int kk = 0; kk < 4; ++kk) {
        bf16x8 bqf = *(const bf16x8*)(Ql + ((kk * 4 + quad) * 2 + (jq >> 2)) * 1024
                                         + ((jq * 16 + ln) & 63) * 16);
        s0 = mfma16(ak[0][kk], bqf, s0);
        s1 = mfma16(ak[1][kk], bqf, s1);
      }
      __builtin_amdgcn_s_setprio(0);
      for (int rr = 0; rr < 4; ++rr) {
        csum[0][rr] += fexp2(s0[rr]);           // Q pre-scaled by C1
        csum[1][rr] += fexp2(s1[rr]);
      }
    }
  }
  for (int i = 0; i < 2; ++i)
    for (int rr = 0; rr < 4; ++rr) {
      float v = csum[i][rr];
      v += __shfl_xor(v, 1, 64); v += __shfl_xor(v, 2, 64);
      v += __shfl_xor(v, 4, 64); v += __shfl_xor(v, 8, 64);
      csum[i][rr] = v;
    }
  if (ln == 0) {
    float* dst = nlg + (size_t)b * 1024 + kt * 128 + wave * 32 + quad * 4;
    for (int i = 0; i < 2; ++i)
      for (int rr = 0; rr < 4; ++rr)
        dst[i * 16 + rr] = -flog2(csum[i][rr]);
  }
}

// ============================================================================
// Kernel 3: fused attention, QK software-pipelined one tile ahead.
// grid(64 b, 8 qt), block 256 (4 waves x 32q), 2 blocks/CU.
// bufK/bufV dbuf-2 (K prefetch 2 ahead, V 1 ahead); sacc ping-pong sA/sB.
// Per iter: wait+barrier, issue K(t+2)/V(t+1), QK(t+1) || exp(t), PV(t).
// ============================================================================
__global__ __launch_bounds__(256, 2) void k_attn(
    const bf16* __restrict__ Qb, const bf16* __restrict__ Kb, const bf16* __restrict__ VT,
    const float* __restrict__ nlg, float* __restrict__ out)
{
  __shared__ char bufK[2][16384];
  __shared__ char bufV[2][16384];
  __shared__ float nll[1024];
  __shared__ float redm[4][128];

  const int b = blockIdx.x, qt = blockIdx.y;
  const int tid = threadIdx.x, lane = tid & 63, wave = tid >> 6;
  const int ln = lane & 15, quad = lane >> 4;

  *(float4*)&nll[tid * 4] = *(const float4*)(nlg + (size_t)b * 1024 + tid * 4);

  const bf16* qtile = Qb + ((size_t)b * 8 + qt) * 16384;
  bf16x8 bq_[2][4];                             // wave's 32 q-rows, full d
  for (int j = 0; j < 2; ++j)
    for (int kk = 0; kk < 4; ++kk)
      bq_[j][kk] = *(const bf16x8*)(qtile + (kk * 4 + quad) * 1024 + (wave * 32 + j * 16 + ln) * 8);

  const char* kb_b = (const char*)(Kb + (size_t)b * 8 * 16384);
  const char* vt_b = (const char*)(VT + (size_t)b * 8 * 16384);

#define K_DMA(t) do {                                                            \
    const char* ksrc = kb_b + (size_t)((t) >> 1) * 32768 + ((t) & 1) * 1024;     \
    char* dk = bufK[(t) & 1];                                                    \
    for (int c = 0; c < 4; ++c) {                                                \
      int ch = wave * 4 + c;                                                     \
      GLDS16(ksrc + ch * 2048 + lane * 16, dk + ch * 1024);                      \
    }                                                                            \
  } while (0)
#define V_DMA(t) do {                                                            \
    const char* vsrc = vt_b + (size_t)((t) >> 1) * 32768 + ((t) & 1) * 16384;    \
    char* dv = bufV[(t) & 1];                                                    \
    for (int c = 0; c < 4; ++c) {                                                \
      int ch = wave * 4 + c;                                                     \
      GLDS16(vsrc + (ch >> 1) * 2048 + (ch & 1) * 1024 + lane * 16,              \
             dv + ch * 1024);                                                    \
    }                                                                            \
  } while (0)

  // QK for tile tt into SN (C-init = -log2 colsum; row rr of frag i is
  // k = tt*64 + i*16 + quad*4 + rr).
#define QK(tt, SN) do {                                                          \
    const char* Kl = bufK[(tt) & 1];                                             \
    _Pragma("unroll")                                                            \
    for (int i = 0; i < 4; ++i) {                                                \
      float4 L4 = *(float4*)&nll[(tt) * 64 + i * 16 + quad * 4];                 \
      f32x4 ini = { L4.x, L4.y, L4.z, L4.w };                                    \
      SN[i][0] = ini; SN[i][1] = ini;                                            \
    }                                                                            \
    __builtin_amdgcn_s_setprio(1);                                               \
    _Pragma("unroll")                                                            \
    for (int kk = 0; kk < 4; ++kk) {                                             \
      bf16x8 ak[4];                                                              \
      _Pragma("unroll")                                                          \
      for (int i = 0; i < 4; ++i)                                                \
        ak[i] = *(const bf16x8*)(Kl + (kk * 4 + quad) * 1024 + (i * 16 + ln) * 16); \
      _Pragma("unroll")                                                          \
      for (int i = 0; i < 4; ++i) {                                              \
        SN[i][0] = mfma16(ak[i], bq_[0][kk], SN[i][0]);                          \
        SN[i][1] = mfma16(ak[i], bq_[1][kk], SN[i][1]);                          \
      }                                                                          \
    }                                                                            \
    __builtin_amdgcn_s_setprio(0);                                               \
  } while (0)

  // exp + PV for tile tt from SC (interleaved per 32-k half).
#define EXPPV(tt, SC) do {                                                       \
    const char* Vl = bufV[(tt) & 1];                                             \
    _Pragma("unroll")                                                            \
    for (int s = 0; s < 2; ++s) {                                                \
      f32x4 lo0 = SC[2 * s][0], hi0 = SC[2 * s + 1][0];                          \
      f32x4 lo1 = SC[2 * s][1], hi1 = SC[2 * s + 1][1];                          \
      bf16x8 pf0 = bf16x8{                                                       \
        (bf16)fexp2(lo0[0]), (bf16)fexp2(lo0[1]), (bf16)fexp2(lo0[2]), (bf16)fexp2(lo0[3]), \
        (bf16)fexp2(hi0[0]), (bf16)fexp2(hi0[1]), (bf16)fexp2(hi0[2]), (bf16)fexp2(hi0[3]) }; \
      bf16x8 pf1 = bf16x8{                                                       \
        (bf16)fexp2(lo1[0]), (bf16)fexp2(lo1[1]), (bf16)fexp2(lo1[2]), (bf16)fexp2(lo1[3]), \
        (bf16)fexp2(hi1[0]), (bf16)fexp2(hi1[1]), (bf16)fexp2(hi1[2]), (bf16)fexp2(hi1[3]) }; \
      _Pragma("unroll")                                                          \
      for (int j2 = 0; j2 < 8; ++j2) {                                           \
        bf16x8 bv_ = *(const bf16x8*)(Vl + ((s * 4 + quad) * 2 + (j2 >> 2)) * 1024 \
                                         + ((j2 * 16 + ln) & 63) * 16);          \
        oacc[0][j2] = mfma16(pf0, bv_, oacc[0][j2]);                             \
        oacc[1][j2] = mfma16(pf1, bv_, oacc[1][j2]);                             \
      }                                                                          \
    }                                                                            \
  } while (0)

  // One pipelined step: tile t uses CUR sacc; QK(t+1) fills NXT.
#define STEP(t, CUR, NXT) do {                                                   \
    WAITN0();                                                                    \
    __syncthreads();                                                             \
    if ((t) < 14) K_DMA((t) + 2);                                                \
    if ((t) < 15) V_DMA((t) + 1);                                                \
    if ((t) < 15) QK((t) + 1, NXT);                                              \
    EXPPV((t), CUR);                                                             \
  } while (0)

  f32x4 oacc[2][8] = {};
  f32x4 sA[4][2], sB[4][2];

  K_DMA(0);
  WAITN0();
  __syncthreads();                              // K(0) visible to all waves
  K_DMA(1); V_DMA(0);                           // land during QK(0)
  QK(0, sA);

  for (int tp = 0; tp < 8; ++tp) {
    STEP(2 * tp,     sA, sB);
    STEP(2 * tp + 1, sB, sA);
  }
#undef STEP
#undef EXPPV
#undef QK
#undef K_DMA
#undef V_DMA

  // max over this block's 128 q rows, per output column d
  for (int j2 = 0; j2 < 8; ++j2) {
    float m = -3.4e38f;
    for (int j = 0; j < 2; ++j)
      for (int rr = 0; rr < 4; ++rr)
        m = fmaxf(m, oacc[j][j2][rr]);
    m = fmaxf(m, __shfl_xor(m, 16, 64));
    m = fmaxf(m, __shfl_xor(m, 32, 64));
    if (lane < 16) redm[wave][j2 * 16 + ln] = m;
  }
  __syncthreads();
  if (tid < 128) {
    float m = fmaxf(fmaxf(redm[0][tid], redm[1][tid]), fmaxf(redm[2][tid], redm[3][tid]));
    // sign-aware integer atomic max (IEEE total order); out pre-init'd to -inf
    float* addr = out + (size_t)b * 128 + tid;
    if (m >= 0.0f) atomicMax((int*)addr, __float_as_int(m));
    else           atomicMin((unsigned int*)addr, __float_as_uint(m));
  }
}

// ============================================================================
extern "C" void kernel_launch(void* const* d_in, const int* in_sizes, int n_in,
                              void* d_out, int out_size, void* d_ws, size_t ws_size,
                              hipStream_t stream) {
  const float* q  = (const float*)d_in[0];
  const float* Wq = (const float*)d_in[1];
  const float* bq = (const float*)d_in[2];
  const float* Wk = (const float*)d_in[3];
  const float* bk = (const float*)d_in[4];
  const float* Wv = (const float*)d_in[5];
  const float* bv = (const float*)d_in[6];
  float* out = (float*)d_out;

  char* ws = (char*)d_ws;
  bf16*  Qb    = (bf16*)(ws);                         // 16 MB granule tiles [s][d]
  bf16*  Kb    = (bf16*)(ws + (16u << 20));           // 16 MB
  bf16*  VT    = (bf16*)(ws + (32u << 20));           // 16 MB (V^T, row-permuted)
  float* nlg   = (float*)(ws + (48u << 20));          // 256 KB [64][1024]  -log2(colsum)
  bf16*  Wc    = (bf16*)(ws + (49u << 20));           // 192 KB [3][32][128][8]

  k_prep <<<48,           256, 0, stream>>>(Wq, Wk, Wv, Wc, out);
  k_qkv  <<<dim3(1024),   256, 0, stream>>>(q, Wc, bq, bk, bv, Qb, Kb, VT);
  k_stats<<<dim3(64, 8),  256, 0, stream>>>(Qb, Kb, nlg);
  k_attn <<<dim3(64, 8),  256, 0, stream>>>(Qb, Kb, VT, nlg, out);
}

// Round 15
// 88.129 us; speedup vs baseline: 1.2196x; 1.2196x over previous
//
#include <hip/hip_runtime.h>

// ---- types -----------------------------------------------------------------
typedef __bf16 bf16;
typedef __attribute__((ext_vector_type(8))) __bf16 bf16x8;
typedef __attribute__((ext_vector_type(4))) __bf16 bf16x4;
typedef __attribute__((ext_vector_type(4))) float  f32x4;

static __device__ __forceinline__ f32x4 mfma16(bf16x8 a, bf16x8 b, f32x4 c) {
  return __builtin_amdgcn_mfma_f32_16x16x32_bf16(a, b, c, 0, 0, 0);
}
static __device__ __forceinline__ float fexp2(float x) {
  return __builtin_amdgcn_exp2f(x);
}
static __device__ __forceinline__ float flog2(float x) {
  return __builtin_amdgcn_logf(x);
}

// exp(s/sqrt(128)) = exp2(s * C1). C1 folded into Wq/bq at prep time.
#define EXP_C1 (1.4426950408889634f / 11.313708498984760f)

// async global->LDS, 16B/lane; dst base is wave-uniform, HW adds lane*16.
typedef const __attribute__((address_space(1))) unsigned int gas_u32;
typedef __attribute__((address_space(3))) unsigned int las_u32;
#define GLDS16(gp, lp) __builtin_amdgcn_global_load_lds((gas_u32*)(gp), (las_u32*)(lp), 16, 0, 0)

// RACE FIX (keep): drain own vmcnt BEFORE s_barrier so cross-wave DMA
// completion is guaranteed.
#define WAITN0() __asm__ volatile("s_waitcnt vmcnt(0)" ::: "memory")

// Granule-major tile (128 rows x 128 cols bf16, 32KB): elem(r,c) = (c>>3)*1024 + r*8 + (c&7).
// V is ROW-PERMUTED (k_qkv epilogue) so the PV MFMA consumes the QK^T
// C-fragment from registers: slot (quad,e) of 32-block s holds V row
// k = 32s + quad*4 + (e&3) + 16*(e>>2).
//
// XCD SWIZZLE: k_stats/k_attn grids are (64 b, 8 qt) with b on X. Same-b
// blocks have linear ids stride 64 (== 0 mod 8 XCDs) -> same XCD L2.
//
// r20->r21 post-mortem: no-LDS k_qkv (r20) collapsed to 65us — per-lane 32B
// at 1KB row stride fragments each wave load into 64 L2 requests (request-
// rate bound). Reverted. Elimination so far: occupancy (r7/r8), DMA depth
// (r9), reg prefetch (r12-15 spill), staging mechanism (r18 clean+no-change),
// W-latency (r19 +0.4), LDS itself (r20 worse). Remaining suspect is
// ARITHMETIC: grid 1024 @ 4 blocks/CU = exactly ONE residency generation ->
// all blocks stage together / compute together / store together; no
// cross-generation overlap exists. r21: 32-row tiles -> grid 2048 -> 8
// generations/CU; successor blocks stage while siblings compute. Fused
// QKV compute (r20-verified math), no W prefetch (VGPR head-room).
// Pre-committed: unchanged dur -> k_qkv declared plateaued.

// ============================================================================
// Kernel 0: prep. W[3][128][256] fp32 -> Wc[3][32 g][128 n][8] bf16.
// Wq additionally scaled by C1. Also initializes out[8192] = -inf for the
// k_attn atomic-max epilogue.
// ============================================================================
__global__ __launch_bounds__(256) void k_prep(
    const float* __restrict__ Wq, const float* __restrict__ Wk,
    const float* __restrict__ Wv, bf16* __restrict__ Wc, float* __restrict__ out)
{
  int id = blockIdx.x * 256 + threadIdx.x;      // 48 blocks = 3*4096
  if (id < 8192) out[id] = -__builtin_inff();
  int proj = id >> 12, r = id & 4095;
  int g = r >> 7, n = r & 127;
  const float* W = proj == 0 ? Wq : proj == 1 ? Wk : Wv;
  const float sc = (proj == 0) ? EXP_C1 : 1.0f;
  const float4* src = (const float4*)(W + n * 256 + g * 8);
  float4 a = src[0], b = src[1];
  bf16x8 o = { (bf16)(a.x * sc), (bf16)(a.y * sc), (bf16)(a.z * sc), (bf16)(a.w * sc),
               (bf16)(b.x * sc), (bf16)(b.y * sc), (bf16)(b.z * sc), (bf16)(b.w * sc) };
  *(bf16x8*)(Wc + (size_t)proj * 32768 + g * 1024 + n * 8) = o;
}

// ============================================================================
// Kernel 1: QKV projection. grid(2048) x 256 thr, 32-row tiles, 4 blocks/CU
// -> 8 generations/CU for cross-generation stage/compute overlap.
// Fused: one ax LDS read feeds Q,K,V accumulators (12 MFMA/kk/wave).
// ============================================================================
__global__ __launch_bounds__(256, 4) void k_qkv(
    const float* __restrict__ q, const bf16* __restrict__ Wc,
    const float* __restrict__ bq, const float* __restrict__ bk, const float* __restrict__ bv,
    bf16* __restrict__ Qb, bf16* __restrict__ Kb, bf16* __restrict__ VT)
{
  __shared__ bf16 Al[32 * 260];   // 32 x-granule chunks (32 rows), stride 260 elems

  const int tid = threadIdx.x, lane = tid & 63, wave = tid >> 6;
  const int ln = lane & 15, quad = lane >> 4;
  const int wc = wave;                          // 1x4 waves: 32 rows x 32 cols
  const int m0 = blockIdx.x * 32;

  { // stage A: coalesced float4 -> bf16 chunks (32 rows x 256 f32 = 32KB)
    const float* src = q + (size_t)m0 * 256;
    for (int it = 0; it < 8; ++it) {
      int f = it * 1024 + tid * 4;
      int r = f >> 8, c = f & 255;
      float4 v = *(const float4*)(src + f);
      bf16x4 o = { (bf16)v.x, (bf16)v.y, (bf16)v.z, (bf16)v.w };
      *(bf16x4*)&Al[(c >> 3) * 260 + r * 8 + (c & 7)] = o;
    }
  }
  __syncthreads();

  const int b = m0 >> 10, st = (m0 & 1023) >> 7, s_off = m0 & 127;
  const size_t tbase = ((size_t)b * 8 + st) * 16384;

  f32x4 aQ[2][2] = {}, aK[2][2] = {}, aV[2][2] = {};
  for (int kk = 0; kk < 8; ++kk) {
    int g = kk * 4 + quad;
    bf16x8 ax[2];
    #pragma unroll
    for (int t = 0; t < 2; ++t)
      ax[t] = *(const bf16x8*)&Al[g * 260 + (t * 16 + ln) * 8];
    bf16x8 bwQ[2], bwK[2], bwV[2];
    #pragma unroll
    for (int t2 = 0; t2 < 2; ++t2) {
      const int off = g * 1024 + (wc * 32 + t2 * 16 + ln) * 8;
      bwQ[t2] = *(const bf16x8*)(Wc + off);
      bwK[t2] = *(const bf16x8*)(Wc + 32768 + off);
      bwV[t2] = *(const bf16x8*)(Wc + 65536 + off);
    }
    __builtin_amdgcn_s_setprio(1);
    #pragma unroll
    for (int i = 0; i < 2; ++i)
      #pragma unroll
      for (int j = 0; j < 2; ++j) {
        aQ[i][j] = mfma16(bwQ[i], ax[j], aQ[i][j]);   // D[d][s]
        aK[i][j] = mfma16(bwK[i], ax[j], aK[i][j]);
      }
    #pragma unroll
    for (int i = 0; i < 2; ++i)
      #pragma unroll
      for (int j = 0; j < 2; ++j)
        aV[i][j] = mfma16(ax[i], bwV[j], aV[i][j]);   // D[s][d]
    __builtin_amdgcn_s_setprio(0);
  }

  // Q,K epilogue: granule-major [s][d]; regs = 4 consecutive d -> bf16x4
  for (int p = 0; p < 2; ++p) {
    bf16* dst = (p == 0 ? Qb : Kb) + tbase;
    const float* bias = p == 0 ? bq : bk;
    for (int i = 0; i < 2; ++i) {
      float4 b4 = *(const float4*)&bias[wc * 32 + i * 16 + quad * 4];
      if (p == 0) { b4.x *= EXP_C1; b4.y *= EXP_C1; b4.z *= EXP_C1; b4.w *= EXP_C1; }
      int gd = wc * 4 + i * 2 + (quad >> 1);    // d-granule
      int e0 = (quad & 1) * 4;
      for (int j = 0; j < 2; ++j) {
        int s = s_off + j * 16 + ln;
        const f32x4 a_ = p == 0 ? aQ[i][j] : aK[i][j];
        bf16x4 o = { (bf16)(a_[0] + b4.x), (bf16)(a_[1] + b4.y),
                     (bf16)(a_[2] + b4.z), (bf16)(a_[3] + b4.w) };
        *(bf16x4*)&dst[(size_t)gd * 1024 + (size_t)s * 8 + e0] = o;
      }
    }
  }
  { // V epilogue: [s-granule][d][8], ROW-PERMUTED
    bf16* dst = VT + tbase;
    for (int j = 0; j < 2; ++j) {
      int d = wc * 32 + j * 16 + ln;
      float bb = bv[d];
      for (int i = 0; i < 2; ++i) {
        int s0 = s_off + i * 16 + quad * 4;
        int G  = (s0 >> 5) * 4 + ((s0 & 15) >> 2);
        int e0 = (s0 & 16) >> 2;
        bf16x4 o = { (bf16)(aV[i][j][0] + bb), (bf16)(aV[i][j][1] + bb),
                     (bf16)(aV[i][j][2] + bb), (bf16)(aV[i][j][3] + bb) };
        *(bf16x4*)&dst[(size_t)G * 1024 + (size_t)d * 8 + e0] = o;
      }
    }
  }
}

// ============================================================================
// Kernel 2: column stats. grid(64 b, 8 kt), block 256, 2 blocks/CU.
// K-frags register-resident; Q streamed via double-buffered DMA.
// Writes nlg[k] = -log2(colsum) (consumed as QK accumulator init in k_attn).
// ============================================================================
__global__ __launch_bounds__(256, 2) void k_stats(
    const bf16* __restrict__ Qb, const bf16* __restrict__ Kb, float* __restrict__ nlg)
{
  __shared__ char Qbuf[2][32768];
  const int b = blockIdx.x, kt = blockIdx.y;
  const int tid = threadIdx.x, lane = tid & 63, wave = tid >> 6;
  const int ln = lane & 15, quad = lane >> 4;

  const bf16* ktile = Kb + ((size_t)b * 8 + kt) * 16384;
  bf16x8 ak[2][4];                              // wave's 32 k-rows, full d=128
  for (int i = 0; i < 2; ++i)
    for (int kk = 0; kk < 4; ++kk)
      ak[i][kk] = *(const bf16x8*)(ktile + (kk * 4 + quad) * 1024 + (wave * 32 + i * 16 + ln) * 8);

  const char* qb_b = (const char*)(Qb + (size_t)b * 8 * 16384);
  for (int c = 0; c < 8; ++c)                   // prologue DMA q-tile 0
    GLDS16(qb_b + (wave * 8 + c) * 1024 + lane * 16, &Qbuf[0][(wave * 8 + c) * 1024]);

  f32x4 csum[2] = {};
  for (int qt = 0; qt < 8; ++qt) {
    WAITN0();
    __syncthreads();                            // all waves' DMA(qt) complete
    if (qt < 7)
      for (int c = 0; c < 8; ++c)
        GLDS16(qb_b + (size_t)(qt + 1) * 32768 + (wave * 8 + c) * 1024 + lane * 16,
               &Qbuf[(qt + 1) & 1][(wave * 8 + c) * 1024]);
    const char* Ql = Qbuf[qt & 1];
    for (int jq = 0; jq < 8; ++jq) {
      f32x4 s0 = {}, s1 = {};
      __builtin_amdgcn_s_setprio(1);
      for (int kk = 0; kk < 4; ++kk) {
        bf16x8 bqf = *(const bf16x8*)(Ql + ((kk * 4 + quad) * 2 + (jq >> 2)) * 1024
                                         + ((jq * 16 + ln) & 63) * 16);
        s0 = mfma16(ak[0][kk], bqf, s0);
        s1 = mfma16(ak[1][kk], bqf, s1);
      }
      __builtin_amdgcn_s_setprio(0);
      for (int rr = 0; rr < 4; ++rr) {
        csum[0][rr] += fexp2(s0[rr]);           // Q pre-scaled by C1
        csum[1][rr] += fexp2(s1[rr]);
      }
    }
  }
  for (int i = 0; i < 2; ++i)
    for (int rr = 0; rr < 4; ++rr) {
      float v = csum[i][rr];
      v += __shfl_xor(v, 1, 64); v += __shfl_xor(v, 2, 64);
      v += __shfl_xor(v, 4, 64); v += __shfl_xor(v, 8, 64);
      csum[i][rr] = v;
    }
  if (ln == 0) {
    float* dst = nlg + (size_t)b * 1024 + kt * 128 + wave * 32 + quad * 4;
    for (int i = 0; i < 2; ++i)
      for (int rr = 0; rr < 4; ++rr)
        dst[i * 16 + rr] = -flog2(csum[i][rr]);
  }
}

// ============================================================================
// Kernel 3: fused attention, QK software-pipelined one tile ahead.
// grid(64 b, 8 qt), block 256 (4 waves x 32q), 2 blocks/CU.
// bufK/bufV dbuf-2 (K prefetch 2 ahead, V 1 ahead); sacc ping-pong sA/sB.
// Per iter: wait+barrier, issue K(t+2)/V(t+1), QK(t+1) || exp(t), PV(t).
// ============================================================================
__global__ __launch_bounds__(256, 2) void k_attn(
    const bf16* __restrict__ Qb, const bf16* __restrict__ Kb, const bf16* __restrict__ VT,
    const float* __restrict__ nlg, float* __restrict__ out)
{
  __shared__ char bufK[2][16384];
  __shared__ char bufV[2][16384];
  __shared__ float nll[1024];
  __shared__ float redm[4][128];

  const int b = blockIdx.x, qt = blockIdx.y;
  const int tid = threadIdx.x, lane = tid & 63, wave = tid >> 6;
  const int ln = lane & 15, quad = lane >> 4;

  *(float4*)&nll[tid * 4] = *(const float4*)(nlg + (size_t)b * 1024 + tid * 4);

  const bf16* qtile = Qb + ((size_t)b * 8 + qt) * 16384;
  bf16x8 bq_[2][4];                             // wave's 32 q-rows, full d
  for (int j = 0; j < 2; ++j)
    for (int kk = 0; kk < 4; ++kk)
      bq_[j][kk] = *(const bf16x8*)(qtile + (kk * 4 + quad) * 1024 + (wave * 32 + j * 16 + ln) * 8);

  const char* kb_b = (const char*)(Kb + (size_t)b * 8 * 16384);
  const char* vt_b = (const char*)(VT + (size_t)b * 8 * 16384);

#define K_DMA(t) do {                                                            \
    const char* ksrc = kb_b + (size_t)((t) >> 1) * 32768 + ((t) & 1) * 1024;     \
    char* dk = bufK[(t) & 1];                                                    \
    for (int c = 0; c < 4; ++c) {                                                \
      int ch = wave * 4 + c;                                                     \
      GLDS16(ksrc + ch * 2048 + lane * 16, dk + ch * 1024);                      \
    }                                                                            \
  } while (0)
#define V_DMA(t) do {                                                            \
    const char* vsrc = vt_b + (size_t)((t) >> 1) * 32768 + ((t) & 1) * 16384;    \
    char* dv = bufV[(t) & 1];                                                    \
    for (int c = 0; c < 4; ++c) {                                                \
      int ch = wave * 4 + c;                                                     \
      GLDS16(vsrc + (ch >> 1) * 2048 + (ch & 1) * 1024 + lane * 16,              \
             dv + ch * 1024);                                                    \
    }                                                                            \
  } while (0)

  // QK for tile tt into SN (C-init = -log2 colsum; row rr of frag i is
  // k = tt*64 + i*16 + quad*4 + rr).
#define QK(tt, SN) do {                                                          \
    const char* Kl = bufK[(tt) & 1];                                             \
    _Pragma("unroll")                                                            \
    for (int i = 0; i < 4; ++i) {                                                \
      float4 L4 = *(float4*)&nll[(tt) * 64 + i * 16 + quad * 4];                 \
      f32x4 ini = { L4.x, L4.y, L4.z, L4.w };                                    \
      SN[i][0] = ini; SN[i][1] = ini;                                            \
    }                                                                            \
    __builtin_amdgcn_s_setprio(1);                                               \
    _Pragma("unroll")                                                            \
    for (int kk = 0; kk < 4; ++kk) {                                             \
      bf16x8 ak[4];                                                              \
      _Pragma("unroll")                                                          \
      for (int i = 0; i < 4; ++i)                                                \
        ak[i] = *(const bf16x8*)(Kl + (kk * 4 + quad) * 1024 + (i * 16 + ln) * 16); \
      _Pragma("unroll")                                                          \
      for (int i = 0; i < 4; ++i) {                                              \
        SN[i][0] = mfma16(ak[i], bq_[0][kk], SN[i][0]);                          \
        SN[i][1] = mfma16(ak[i], bq_[1][kk], SN[i][1]);                          \
      }                                                                          \
    }                                                                            \
    __builtin_amdgcn_s_setprio(0);                                               \
  } while (0)

  // exp + PV for tile tt from SC (interleaved per 32-k half).
#define EXPPV(tt, SC) do {                                                       \
    const char* Vl = bufV[(tt) & 1];                                             \
    _Pragma("unroll")                                                            \
    for (int s = 0; s < 2; ++s) {                                                \
      f32x4 lo0 = SC[2 * s][0], hi0 = SC[2 * s + 1][0];                          \
      f32x4 lo1 = SC[2 * s][1], hi1 = SC[2 * s + 1][1];                          \
      bf16x8 pf0 = bf16x8{                                                       \
        (bf16)fexp2(lo0[0]), (bf16)fexp2(lo0[1]), (bf16)fexp2(lo0[2]), (bf16)fexp2(lo0[3]), \
        (bf16)fexp2(hi0[0]), (bf16)fexp2(hi0[1]), (bf16)fexp2(hi0[2]), (bf16)fexp2(hi0[3]) }; \
      bf16x8 pf1 = bf16x8{                                                       \
        (bf16)fexp2(lo1[0]), (bf16)fexp2(lo1[1]), (bf16)fexp2(lo1[2]), (bf16)fexp2(lo1[3]), \
        (bf16)fexp2(hi1[0]), (bf16)fexp2(hi1[1]), (bf16)fexp2(hi1[2]), (bf16)fexp2(hi1[3]) }; \
      _Pragma("unroll")                                                          \
      for (int j2 = 0; j2 < 8; ++j2) {                                           \
        bf16x8 bv_ = *(const bf16x8*)(Vl + ((s * 4 + quad) * 2 + (j2 >> 2)) * 1024 \
                                         + ((j2 * 16 + ln) & 63) * 16);          \
        oacc[0][j2] = mfma16(pf0, bv_, oacc[0][j2]);                             \
        oacc[1][j2] = mfma16(pf1, bv_, oacc[1][j2]);                             \
      }                                                                          \
    }                                                                            \
  } while (0)

  // One pipelined step: tile t uses CUR sacc; QK(t+1) fills NXT.
#define STEP(t, CUR, NXT) do {                                                   \
    WAITN0();                                                                    \
    __syncthreads();                                                             \
    if ((t) < 14) K_DMA((t) + 2);                                                \
    if ((t) < 15) V_DMA((t) + 1);                                                \
    if ((t) < 15) QK((t) + 1, NXT);                                              \
    EXPPV((t), CUR);                                                             \
  } while (0)

  f32x4 oacc[2][8] = {};
  f32x4 sA[4][2], sB[4][2];

  K_DMA(0);
  WAITN0();
  __syncthreads();                              // K(0) visible to all waves
  K_DMA(1); V_DMA(0);                           // land during QK(0)
  QK(0, sA);

  for (int tp = 0; tp < 8; ++tp) {
    STEP(2 * tp,     sA, sB);
    STEP(2 * tp + 1, sB, sA);
  }
#undef STEP
#undef EXPPV
#undef QK
#undef K_DMA
#undef V_DMA

  // max over this block's 128 q rows, per output column d
  for (int j2 = 0; j2 < 8; ++j2) {
    float m = -3.4e38f;
    for (int j = 0; j < 2; ++j)
      for (int rr = 0; rr < 4; ++rr)
        m = fmaxf(m, oacc[j][j2][rr]);
    m = fmaxf(m, __shfl_xor(m, 16, 64));
    m = fmaxf(m, __shfl_xor(m, 32, 64));
    if (lane < 16) redm[wave][j2 * 16 + ln] = m;
  }
  __syncthreads();
  if (tid < 128) {
    float m = fmaxf(fmaxf(redm[0][tid], redm[1][tid]), fmaxf(redm[2][tid], redm[3][tid]));
    // sign-aware integer atomic max (IEEE total order); out pre-init'd to -inf
    float* addr = out + (size_t)b * 128 + tid;
    if (m >= 0.0f) atomicMax((int*)addr, __float_as_int(m));
    else           atomicMin((unsigned int*)addr, __float_as_uint(m));
  }
}

// ============================================================================
extern "C" void kernel_launch(void* const* d_in, const int* in_sizes, int n_in,
                              void* d_out, int out_size, void* d_ws, size_t ws_size,
                              hipStream_t stream) {
  const float* q  = (const float*)d_in[0];
  const float* Wq = (const float*)d_in[1];
  const float* bq = (const float*)d_in[2];
  const float* Wk = (const float*)d_in[3];
  const float* bk = (const float*)d_in[4];
  const float* Wv = (const float*)d_in[5];
  const float* bv = (const float*)d_in[6];
  float* out = (float*)d_out;

  char* ws = (char*)d_ws;
  bf16*  Qb    = (bf16*)(ws);                         // 16 MB granule tiles [s][d]
  bf16*  Kb    = (bf16*)(ws + (16u << 20));           // 16 MB
  bf16*  VT    = (bf16*)(ws + (32u << 20));           // 16 MB (V^T, row-permuted)
  float* nlg   = (float*)(ws + (48u << 20));          // 256 KB [64][1024]  -log2(colsum)
  bf16*  Wc    = (bf16*)(ws + (49u << 20));           // 192 KB [3][32][128][8]

  k_prep <<<48,           256, 0, stream>>>(Wq, Wk, Wv, Wc, out);
  k_qkv  <<<dim3(2048),   256, 0, stream>>>(q, Wc, bq, bk, bv, Qb, Kb, VT);
  k_stats<<<dim3(64, 8),  256, 0, stream>>>(Qb, Kb, nlg);
  k_attn <<<dim3(64, 8),  256, 0, stream>>>(Qb, Kb, VT, nlg, out);
}

// Round 16
// 85.968 us; speedup vs baseline: 1.2503x; 1.0251x over previous
//
#include <hip/hip_runtime.h>

// ---- types -----------------------------------------------------------------
typedef __bf16 bf16;
typedef __attribute__((ext_vector_type(8))) __bf16 bf16x8;
typedef __attribute__((ext_vector_type(4))) __bf16 bf16x4;
typedef __attribute__((ext_vector_type(4))) float  f32x4;

static __device__ __forceinline__ f32x4 mfma16(bf16x8 a, bf16x8 b, f32x4 c) {
  return __builtin_amdgcn_mfma_f32_16x16x32_bf16(a, b, c, 0, 0, 0);
}
static __device__ __forceinline__ float fexp2(float x) {
  return __builtin_amdgcn_exp2f(x);
}
static __device__ __forceinline__ float flog2(float x) {
  return __builtin_amdgcn_logf(x);
}

// exp(s/sqrt(128)) = exp2(s * C1). C1 folded into Wq/bq at prep time.
#define EXP_C1 (1.4426950408889634f / 11.313708498984760f)

// async global->LDS, 16B/lane; dst base is wave-uniform, HW adds lane*16.
typedef const __attribute__((address_space(1))) unsigned int gas_u32;
typedef __attribute__((address_space(3))) unsigned int las_u32;
#define GLDS16(gp, lp) __builtin_amdgcn_global_load_lds((gas_u32*)(gp), (las_u32*)(lp), 16, 0, 0)

// RACE FIX (keep): drain own vmcnt BEFORE s_barrier so cross-wave DMA
// completion is guaranteed.
#define WAITN0() __asm__ volatile("s_waitcnt vmcnt(0)" ::: "memory")

// Granule-major tile (128 rows x 128 cols bf16, 32KB): elem(r,c) = (c>>3)*1024 + r*8 + (c&7).
// V is ROW-PERMUTED (k_qkv epilogue) so the PV MFMA consumes the QK^T
// C-fragment from registers: slot (quad,e) of 32-block s holds V row
// k = 32s + quad*4 + (e&3) + 16*(e>>2).
//
// XCD SWIZZLE: k_stats/k_attn grids are (64 b, 8 qt) with b on X. Same-b
// blocks have linear ids stride 64 (== 0 mod 8 XCDs) -> same XCD L2.
//
// r21->r22: FINAL REVERT to the measured session best (r19, 86.35us).
// k_qkv elimination record across 7 structural hypotheses: occupancy
// (r7/r8), DMA depth (r9), reg prefetch (r12-15: allocator spill), staging
// mechanism (r18: clean, dur unchanged), W-latency (r19: +0.4), LDS removal
// (r20: -21us), generation stagger (r21: null). k_qkv is plateaued at
// ~38us with all pipes <31%, FETCH 33.6MB << 67MB q (L3-resident) ->
// distributed issue/latency beyond source-level reach. Locking best state.

// ============================================================================
// Kernel 0: prep. W[3][128][256] fp32 -> Wc[3][32 g][128 n][8] bf16.
// Wq additionally scaled by C1. Also initializes out[8192] = -inf for the
// k_attn atomic-max epilogue.
// ============================================================================
__global__ __launch_bounds__(256) void k_prep(
    const float* __restrict__ Wq, const float* __restrict__ Wk,
    const float* __restrict__ Wv, bf16* __restrict__ Wc, float* __restrict__ out)
{
  int id = blockIdx.x * 256 + threadIdx.x;      // 48 blocks = 3*4096
  if (id < 8192) out[id] = -__builtin_inff();
  int proj = id >> 12, r = id & 4095;
  int g = r >> 7, n = r & 127;
  const float* W = proj == 0 ? Wq : proj == 1 ? Wk : Wv;
  const float sc = (proj == 0) ? EXP_C1 : 1.0f;
  const float4* src = (const float4*)(W + n * 256 + g * 8);
  float4 a = src[0], b = src[1];
  bf16x8 o = { (bf16)(a.x * sc), (bf16)(a.y * sc), (bf16)(a.z * sc), (bf16)(a.w * sc),
               (bf16)(b.x * sc), (bf16)(b.y * sc), (bf16)(b.z * sc), (bf16)(b.w * sc) };
  *(bf16x8*)(Wc + (size_t)proj * 32768 + g * 1024 + n * 8) = o;
}

// ============================================================================
// Kernel 1: QKV projection. grid(1024), block 256, 4 blocks/CU.
// r16 body (stride 520) + r19 depth-2 W register prefetch (16 VGPR).
// ============================================================================
__global__ __launch_bounds__(256, 4) void k_qkv(
    const float* __restrict__ q, const bf16* __restrict__ Wc,
    const float* __restrict__ bq, const float* __restrict__ bk, const float* __restrict__ bv,
    bf16* __restrict__ Qb, bf16* __restrict__ Kb, bf16* __restrict__ VT)
{
  __shared__ bf16 Al[32 * 520];   // 32 x-granule chunks (64 rows), stride 520 elems

  const int tid = threadIdx.x, lane = tid & 63, wave = tid >> 6;
  const int ln = lane & 15, quad = lane >> 4;
  const int wc = wave;                          // 1x4 waves: 64 rows x 32 cols
  const int m0 = blockIdx.x * 64;

  { // stage A: coalesced float4 -> bf16 chunks
    const float* src = q + (size_t)m0 * 256;
    for (int it = 0; it < 16; ++it) {
      int f = it * 1024 + tid * 4;
      int r = f >> 8, c = f & 255;
      float4 v = *(const float4*)(src + f);
      bf16x4 o = { (bf16)v.x, (bf16)v.y, (bf16)v.z, (bf16)v.w };
      *(bf16x4*)&Al[(c >> 3) * 520 + r * 8 + (c & 7)] = o;
    }
  }
  __syncthreads();

  const int b = m0 >> 10, st = (m0 & 1023) >> 7, s_off = m0 & 64;
  const size_t tbase = ((size_t)b * 8 + st) * 16384;

#define BW_LOAD(slot, kkv) do {                                                               \
    bwp[slot][0] = *(const bf16x8*)(W + ((kkv) * 4 + quad) * 1024 + (wc * 32 + ln) * 8);      \
    bwp[slot][1] = *(const bf16x8*)(W + ((kkv) * 4 + quad) * 1024 + (wc * 32 + 16 + ln) * 8); \
  } while (0)

  for (int p = 0; p < 3; ++p) {
    const bf16* W = Wc + (size_t)p * 32768;
    const float* bias = p == 0 ? bq : p == 1 ? bk : bv;
    bf16x8 bwp[2][2];                           // depth-2 W pipeline (16 VGPR)
    BW_LOAD(0, 0);

    if (p < 2) {   // D[d][s]: A=W (m=d), B=X (n=s)
      f32x4 acc[2][4] = {};
      #pragma unroll
      for (int kk = 0; kk < 8; ++kk) {
        int g = kk * 4 + quad;
        bf16x8 ax[4];
        #pragma unroll
        for (int t = 0; t < 4; ++t)
          ax[t] = *(const bf16x8*)&Al[g * 520 + (t * 16 + ln) * 8];
        if (kk < 7) BW_LOAD((kk + 1) & 1, kk + 1);   // prefetch kk+1 under MFMAs
        bf16x8 b0 = bwp[kk & 1][0], b1 = bwp[kk & 1][1];
        #pragma unroll
        for (int j = 0; j < 4; ++j) {
          acc[0][j] = mfma16(b0, ax[j], acc[0][j]);
          acc[1][j] = mfma16(b1, ax[j], acc[1][j]);
        }
      }
      bf16* dst = (p == 0 ? Qb : Kb) + tbase;
      for (int i = 0; i < 2; ++i) {
        float4 b4 = *(const float4*)&bias[wc * 32 + i * 16 + quad * 4];
        if (p == 0) { b4.x *= EXP_C1; b4.y *= EXP_C1; b4.z *= EXP_C1; b4.w *= EXP_C1; }
        int gd = wc * 4 + i * 2 + (quad >> 1);    // d-granule
        int e0 = (quad & 1) * 4;
        for (int j = 0; j < 4; ++j) {
          int s = s_off + j * 16 + ln;
          bf16x4 o = { (bf16)(acc[i][j][0] + b4.x), (bf16)(acc[i][j][1] + b4.y),
                       (bf16)(acc[i][j][2] + b4.z), (bf16)(acc[i][j][3] + b4.w) };
          *(bf16x4*)&dst[(size_t)gd * 1024 + (size_t)s * 8 + e0] = o;
        }
      }
    } else {       // D[s][d]: A=X (m=s), B=W (n=d)
      f32x4 acc[4][2] = {};
      #pragma unroll
      for (int kk = 0; kk < 8; ++kk) {
        int g = kk * 4 + quad;
        bf16x8 ax[4];
        #pragma unroll
        for (int t = 0; t < 4; ++t)
          ax[t] = *(const bf16x8*)&Al[g * 520 + (t * 16 + ln) * 8];
        if (kk < 7) BW_LOAD((kk + 1) & 1, kk + 1);
        bf16x8 b0 = bwp[kk & 1][0], b1 = bwp[kk & 1][1];
        #pragma unroll
        for (int i = 0; i < 4; ++i) {
          acc[i][0] = mfma16(ax[i], b0, acc[i][0]);
          acc[i][1] = mfma16(ax[i], b1, acc[i][1]);
        }
      }
      bf16* dst = VT + tbase;   // V: [s-granule][d][8], ROW-PERMUTED
      for (int j = 0; j < 2; ++j) {
        int d = wc * 32 + j * 16 + ln;
        float bb = bias[d];
        for (int i = 0; i < 4; ++i) {
          int s0 = s_off + i * 16 + quad * 4;
          int G  = (s0 >> 5) * 4 + ((s0 & 15) >> 2);
          int e0 = (s0 & 16) >> 2;
          bf16x4 o = { (bf16)(acc[i][j][0] + bb), (bf16)(acc[i][j][1] + bb),
                       (bf16)(acc[i][j][2] + bb), (bf16)(acc[i][j][3] + bb) };
          *(bf16x4*)&dst[(size_t)G * 1024 + (size_t)d * 8 + e0] = o;
        }
      }
    }
  }
#undef BW_LOAD
}

// ============================================================================
// Kernel 2: column stats. grid(64 b, 8 kt), block 256, 2 blocks/CU.
// K-frags register-resident; Q streamed via double-buffered DMA.
// Writes nlg[k] = -log2(colsum) (consumed as QK accumulator init in k_attn).
// ============================================================================
__global__ __launch_bounds__(256, 2) void k_stats(
    const bf16* __restrict__ Qb, const bf16* __restrict__ Kb, float* __restrict__ nlg)
{
  __shared__ char Qbuf[2][32768];
  const int b = blockIdx.x, kt = blockIdx.y;
  const int tid = threadIdx.x, lane = tid & 63, wave = tid >> 6;
  const int ln = lane & 15, quad = lane >> 4;

  const bf16* ktile = Kb + ((size_t)b * 8 + kt) * 16384;
  bf16x8 ak[2][4];                              // wave's 32 k-rows, full d=128
  for (int i = 0; i < 2; ++i)
    for (int kk = 0; kk < 4; ++kk)
      ak[i][kk] = *(const bf16x8*)(ktile + (kk * 4 + quad) * 1024 + (wave * 32 + i * 16 + ln) * 8);

  const char* qb_b = (const char*)(Qb + (size_t)b * 8 * 16384);
  for (int c = 0; c < 8; ++c)                   // prologue DMA q-tile 0
    GLDS16(qb_b + (wave * 8 + c) * 1024 + lane * 16, &Qbuf[0][(wave * 8 + c) * 1024]);

  f32x4 csum[2] = {};
  for (int qt = 0; qt < 8; ++qt) {
    WAITN0();
    __syncthreads();                            // all waves' DMA(qt) complete
    if (qt < 7)
      for (int c = 0; c < 8; ++c)
        GLDS16(qb_b + (size_t)(qt + 1) * 32768 + (wave * 8 + c) * 1024 + lane * 16,
               &Qbuf[(qt + 1) & 1][(wave * 8 + c) * 1024]);
    const char* Ql = Qbuf[qt & 1];
    for (int jq = 0; jq < 8; ++jq) {
      f32x4 s0 = {}, s1 = {};
      __builtin_amdgcn_s_setprio(1);
      for (int kk = 0; kk < 4; ++kk) {
        bf16x8 bqf = *(const bf16x8*)(Ql + ((kk * 4 + quad) * 2 + (jq >> 2)) * 1024
                                         + ((jq * 16 + ln) & 63) * 16);
        s0 = mfma16(ak[0][kk], bqf, s0);
        s1 = mfma16(ak[1][kk], bqf, s1);
      }
      __builtin_amdgcn_s_setprio(0);
      for (int rr = 0; rr < 4; ++rr) {
        csum[0][rr] += fexp2(s0[rr]);           // Q pre-scaled by C1
        csum[1][rr] += fexp2(s1[rr]);
      }
    }
  }
  for (int i = 0; i < 2; ++i)
    for (int rr = 0; rr < 4; ++rr) {
      float v = csum[i][rr];
      v += __shfl_xor(v, 1, 64); v += __shfl_xor(v, 2, 64);
      v += __shfl_xor(v, 4, 64); v += __shfl_xor(v, 8, 64);
      csum[i][rr] = v;
    }
  if (ln == 0) {
    float* dst = nlg + (size_t)b * 1024 + kt * 128 + wave * 32 + quad * 4;
    for (int i = 0; i < 2; ++i)
      for (int rr = 0; rr < 4; ++rr)
        dst[i * 16 + rr] = -flog2(csum[i][rr]);
  }
}

// ============================================================================
// Kernel 3: fused attention, QK software-pipelined one tile ahead.
// grid(64 b, 8 qt), block 256 (4 waves x 32q), 2 blocks/CU.
// bufK/bufV dbuf-2 (K prefetch 2 ahead, V 1 ahead); sacc ping-pong sA/sB.
// Per iter: wait+barrier, issue K(t+2)/V(t+1), QK(t+1) || exp(t), PV(t).
// ============================================================================
__global__ __launch_bounds__(256, 2) void k_attn(
    const bf16* __restrict__ Qb, const bf16* __restrict__ Kb, const bf16* __restrict__ VT,
    const float* __restrict__ nlg, float* __restrict__ out)
{
  __shared__ char bufK[2][16384];
  __shared__ char bufV[2][16384];
  __shared__ float nll[1024];
  __shared__ float redm[4][128];

  const int b = blockIdx.x, qt = blockIdx.y;
  const int tid = threadIdx.x, lane = tid & 63, wave = tid >> 6;
  const int ln = lane & 15, quad = lane >> 4;

  *(float4*)&nll[tid * 4] = *(const float4*)(nlg + (size_t)b * 1024 + tid * 4);

  const bf16* qtile = Qb + ((size_t)b * 8 + qt) * 16384;
  bf16x8 bq_[2][4];                             // wave's 32 q-rows, full d
  for (int j = 0; j < 2; ++j)
    for (int kk = 0; kk < 4; ++kk)
      bq_[j][kk] = *(const bf16x8*)(qtile + (kk * 4 + quad) * 1024 + (wave * 32 + j * 16 + ln) * 8);

  const char* kb_b = (const char*)(Kb + (size_t)b * 8 * 16384);
  const char* vt_b = (const char*)(VT + (size_t)b * 8 * 16384);

#define K_DMA(t) do {                                                            \
    const char* ksrc = kb_b + (size_t)((t) >> 1) * 32768 + ((t) & 1) * 1024;     \
    char* dk = bufK[(t) & 1];                                                    \
    for (int c = 0; c < 4; ++c) {                                                \
      int ch = wave * 4 + c;                                                     \
      GLDS16(ksrc + ch * 2048 + lane * 16, dk + ch * 1024);                      \
    }                                                                            \
  } while (0)
#define V_DMA(t) do {                                                            \
    const char* vsrc = vt_b + (size_t)((t) >> 1) * 32768 + ((t) & 1) * 16384;    \
    char* dv = bufV[(t) & 1];                                                    \
    for (int c = 0; c < 4; ++c) {                                                \
      int ch = wave * 4 + c;                                                     \
      GLDS16(vsrc + (ch >> 1) * 2048 + (ch & 1) * 1024 + lane * 16,              \
             dv + ch * 1024);                                                    \
    }                                                                            \
  } while (0)

  // QK for tile tt into SN (C-init = -log2 colsum; row rr of frag i is
  // k = tt*64 + i*16 + quad*4 + rr).
#define QK(tt, SN) do {                                                          \
    const char* Kl = bufK[(tt) & 1];                                             \
    _Pragma("unroll")                                                            \
    for (int i = 0; i < 4; ++i) {                                                \
      float4 L4 = *(float4*)&nll[(tt) * 64 + i * 16 + quad * 4];                 \
      f32x4 ini = { L4.x, L4.y, L4.z, L4.w };                                    \
      SN[i][0] = ini; SN[i][1] = ini;                                            \
    }                                                                            \
    __builtin_amdgcn_s_setprio(1);                                               \
    _Pragma("unroll")                                                            \
    for (int kk = 0; kk < 4; ++kk) {                                             \
      bf16x8 ak[4];                                                              \
      _Pragma("unroll")                                                          \
      for (int i = 0; i < 4; ++i)                                                \
        ak[i] = *(const bf16x8*)(Kl + (kk * 4 + quad) * 1024 + (i * 16 + ln) * 16); \
      _Pragma("unroll")                                                          \
      for (int i = 0; i < 4; ++i) {                                              \
        SN[i][0] = mfma16(ak[i], bq_[0][kk], SN[i][0]);                          \
        SN[i][1] = mfma16(ak[i], bq_[1][kk], SN[i][1]);                          \
      }                                                                          \
    }                                                                            \
    __builtin_amdgcn_s_setprio(0);                                               \
  } while (0)

  // exp + PV for tile tt from SC (interleaved per 32-k half).
#define EXPPV(tt, SC) do {                                                       \
    const char* Vl = bufV[(tt) & 1];                                             \
    _Pragma("unroll")                                                            \
    for (int s = 0; s < 2; ++s) {                                                \
      f32x4 lo0 = SC[2 * s][0], hi0 = SC[2 * s + 1][0];                          \
      f32x4 lo1 = SC[2 * s][1], hi1 = SC[2 * s + 1][1];                          \
      bf16x8 pf0 = bf16x8{                                                       \
        (bf16)fexp2(lo0[0]), (bf16)fexp2(lo0[1]), (bf16)fexp2(lo0[2]), (bf16)fexp2(lo0[3]), \
        (bf16)fexp2(hi0[0]), (bf16)fexp2(hi0[1]), (bf16)fexp2(hi0[2]), (bf16)fexp2(hi0[3]) }; \
      bf16x8 pf1 = bf16x8{                                                       \
        (bf16)fexp2(lo1[0]), (bf16)fexp2(lo1[1]), (bf16)fexp2(lo1[2]), (bf16)fexp2(lo1[3]), \
        (bf16)fexp2(hi1[0]), (bf16)fexp2(hi1[1]), (bf16)fexp2(hi1[2]), (bf16)fexp2(hi1[3]) }; \
      _Pragma("unroll")                                                          \
      for (int j2 = 0; j2 < 8; ++j2) {                                           \
        bf16x8 bv_ = *(const bf16x8*)(Vl + ((s * 4 + quad) * 2 + (j2 >> 2)) * 1024 \
                                         + ((j2 * 16 + ln) & 63) * 16);          \
        oacc[0][j2] = mfma16(pf0, bv_, oacc[0][j2]);                             \
        oacc[1][j2] = mfma16(pf1, bv_, oacc[1][j2]);                             \
      }                                                                          \
    }                                                                            \
  } while (0)

  // One pipelined step: tile t uses CUR sacc; QK(t+1) fills NXT.
#define STEP(t, CUR, NXT) do {                                                   \
    WAITN0();                                                                    \
    __syncthreads();                                                             \
    if ((t) < 14) K_DMA((t) + 2);                                                \
    if ((t) < 15) V_DMA((t) + 1);                                                \
    if ((t) < 15) QK((t) + 1, NXT);                                              \
    EXPPV((t), CUR);                                                             \
  } while (0)

  f32x4 oacc[2][8] = {};
  f32x4 sA[4][2], sB[4][2];

  K_DMA(0);
  WAITN0();
  __syncthreads();                              // K(0) visible to all waves
  K_DMA(1); V_DMA(0);                           // land during QK(0)
  QK(0, sA);

  for (int tp = 0; tp < 8; ++tp) {
    STEP(2 * tp,     sA, sB);
    STEP(2 * tp + 1, sB, sA);
  }
#undef STEP
#undef EXPPV
#undef QK
#undef K_DMA
#undef V_DMA

  // max over this block's 128 q rows, per output column d
  for (int j2 = 0; j2 < 8; ++j2) {
    float m = -3.4e38f;
    for (int j = 0; j < 2; ++j)
      for (int rr = 0; rr < 4; ++rr)
        m = fmaxf(m, oacc[j][j2][rr]);
    m = fmaxf(m, __shfl_xor(m, 16, 64));
    m = fmaxf(m, __shfl_xor(m, 32, 64));
    if (lane < 16) redm[wave][j2 * 16 + ln] = m;
  }
  __syncthreads();
  if (tid < 128) {
    float m = fmaxf(fmaxf(redm[0][tid], redm[1][tid]), fmaxf(redm[2][tid], redm[3][tid]));
    // sign-aware integer atomic max (IEEE total order); out pre-init'd to -inf
    float* addr = out + (size_t)b * 128 + tid;
    if (m >= 0.0f) atomicMax((int*)addr, __float_as_int(m));
    else           atomicMin((unsigned int*)addr, __float_as_uint(m));
  }
}

// ============================================================================
extern "C" void kernel_launch(void* const* d_in, const int* in_sizes, int n_in,
                              void* d_out, int out_size, void* d_ws, size_t ws_size,
                              hipStream_t stream) {
  const float* q  = (const float*)d_in[0];
  const float* Wq = (const float*)d_in[1];
  const float* bq = (const float*)d_in[2];
  const float* Wk = (const float*)d_in[3];
  const float* bk = (const float*)d_in[4];
  const float* Wv = (const float*)d_in[5];
  const float* bv = (const float*)d_in[6];
  float* out = (float*)d_out;

  char* ws = (char*)d_ws;
  bf16*  Qb    = (bf16*)(ws);                         // 16 MB granule tiles [s][d]
  bf16*  Kb    = (bf16*)(ws + (16u << 20));           // 16 MB
  bf16*  VT    = (bf16*)(ws + (32u << 20));           // 16 MB (V^T, row-permuted)
  float* nlg   = (float*)(ws + (48u << 20));          // 256 KB [64][1024]  -log2(colsum)
  bf16*  Wc    = (bf16*)(ws + (49u << 20));           // 192 KB [3][32][128][8]

  k_prep <<<48,           256, 0, stream>>>(Wq, Wk, Wv, Wc, out);
  k_qkv  <<<dim3(1024),   256, 0, stream>>>(q, Wc, bq, bk, bv, Qb, Kb, VT);
  k_stats<<<dim3(64, 8),  256, 0, stream>>>(Qb, Kb, nlg);
  k_attn <<<dim3(64, 8),  256, 0, stream>>>(Qb, Kb, VT, nlg, out);
}